// Round 10
// baseline (233.429 us; speedup 1.0000x reference)
//
#include <hip/hip_runtime.h>
#include <hip/hip_bf16.h>

typedef __attribute__((ext_vector_type(8))) short bf16x8;
typedef __attribute__((ext_vector_type(4))) float f32x4;

__device__ __forceinline__ float sigmoidf_(float x){ return 1.0f/(1.0f+__expf(-x)); }
__device__ __forceinline__ float tanhf_(float x){ return 1.0f - 2.0f/(1.0f+__expf(2.0f*x)); }
__device__ __forceinline__ unsigned short f2bf(float f){
    __hip_bfloat16 b = __float2bfloat16(f);
    return *reinterpret_cast<unsigned short*>(&b);
}
__device__ __forceinline__ float bf2f(unsigned short u){
    __hip_bfloat16 b = *reinterpret_cast<__hip_bfloat16*>(&u);
    return __bfloat162float(b);
}

// ---------------------------------------------------------------------------
// Layouts:
//  Bg (ushort): 68 slabs of 21504 ush (= 43008 B = 2688 float4 each).
//   slab = [plane hi/lo][21 slots][4 qr][16 j][8 e]; plane stride 10752 ush.
//   Slabs 0..63  = per-o ks0 slabs: slots 0..20 = tiles 0..20 (r,z,i_n);
//     k rows: kk<18 -> W_ih[gate][100+kk]; kk==18 -> BIAS (old gio value:
//     b_ih(+b_hh for r/z) + obs[o].W_ih[:, :100]), hi/lo split; kk>18 -> 0.
//     A supplies 1.0 at k=18 so Ahi*Bhi + Ahi*Blo reconstructs fp32 bias.
//   Slabs 64..67 = H ksteps 1..4: kh=(ks-1)*32+kk<100 of W_hh;
//     slots 0..13 -> tiles 0..13 (r,z); slots 14..20 -> tiles 21..27 (hn).
//     REGION 3 (hn) uses gate rows 200+u (same n-gate rows as region 2)!
//  h (float32): [rows][128]; cols 0..111 = units (100..111 compute to 0),
//   cols 112..127 zeroed explicitly. h_n's bias b_hh[200+u] is applied in the
//   epilogue (one fma), not via B.
// ---------------------------------------------------------------------------
__global__ __launch_bounds__(64) void precompute_kernel(
    const float* __restrict__ obs, const float* __restrict__ W_ih,
    const float* __restrict__ W_hh, const float* __restrict__ b_ih,
    const float* __restrict__ b_hh, const float* __restrict__ W1,
    const float* __restrict__ W2,
    unsigned short* __restrict__ Bg,
    float* __restrict__ W1T, float* __restrict__ W2T)
{
    int t = blockIdx.x * 64 + threadIdx.x;
    if (t < 688128) { // ks0 slabs, one per o: 64 * 10752 positions (per plane)
        int o = t / 10752, r = t % 10752;
        int s = r / 512, r2 = r % 512;
        int j = r2 / 32, kk = r2 % 32;
        int region = s / 7;                 // 0=r,1=z,2=i_n
        int u = (s % 7) * 16 + j;
        float wv = 0.f;
        if (u < 100) {
            int gate = region * 100 + u;
            if (kk < 18) {
                wv = W_ih[(size_t)gate * 118 + 100 + kk];
            } else if (kk == 18) { // bias row (old gio)
                wv = b_ih[gate] + (region < 2 ? b_hh[gate] : 0.f);
                const float* orow = obs + o * 100;
                const float* wrow = W_ih + (size_t)gate * 118;
                for (int k = 0; k < 100; ++k) wv = fmaf(orow[k], wrow[k], wv);
            }
        }
        unsigned short h = f2bf(wv);
        unsigned short l = f2bf(wv - bf2f(h));
        int qr = kk >> 3, e = kk & 7;
        size_t base = (size_t)o * 21504 + (size_t)((s * 4 + qr) * 16 + j) * 8 + e;
        Bg[base] = h;
        Bg[base + 10752] = l;
        return;
    }
    t -= 688128;
    if (t < 43008) { // H slabs (ks 1..4): 4 * 10752 positions
        int ks = 1 + t / 10752, r = t % 10752;
        int s = r / 512, r2 = r % 512;
        int j = r2 / 32, kk = r2 % 32;
        int tt = (s < 14) ? s : s + 7;
        int region = tt / 7;
        int u = (tt % 7) * 16 + j;
        float wv = 0.f;
        if (u < 100) {
            // region 3 (h_n) uses the SAME n-gate rows (200+u) as region 2
            int gate = (region == 3 ? 2 : region) * 100 + u;
            int kh = (ks - 1) * 32 + kk;
            if (kh < 100) wv = W_hh[(size_t)gate * 100 + kh];
        }
        unsigned short h = f2bf(wv);
        unsigned short l = f2bf(wv - bf2f(h));
        int qr = kk >> 3, e = kk & 7;
        size_t base = (size_t)(64 + ks - 1) * 21504
                    + (size_t)((s * 4 + qr) * 16 + j) * 8 + e;
        Bg[base] = h;
        Bg[base + 10752] = l;
        return;
    }
    t -= 43008;
    if (t < 5000) { int g = t / 50, j = t % 50; W1T[t] = W1[j * 100 + g]; return; }
    t -= 5000;
    if (t < 1250) { int j = t / 25, i = t % 25; W2T[t] = W2[i * 50 + j]; }
}

// ---------------------------------------------------------------------------
// GRU level via MFMA. Block = NW waves; wave = one 16-cell M-tile.
// acc[28] f32x4 zero-init: tiles 0-6=r, 7-13=z, 14-20=i_n, 21-27=h_n.
// MFMA 16x16x32 bf16: A row=lane&15, k=(lane>>4)*8+e; B col=lane&15, same k;
// D col=lane&15, row=(lane>>4)*4+reg.  Split: D += Ahi*Bhi + Alo*Bhi + Ahi*Blo.
// h is fp32 [rows][128]; A hi/lo split is done in-register per kstep.
// ---------------------------------------------------------------------------
template<bool HASH, int NW>
__global__ __launch_bounds__(NW * 64) void gru_level(
    const unsigned short* __restrict__ Bg,  // 68 slabs (see layout)
    const float* __restrict__ bhh,          // b_hh (for h_n bias rows 200+u)
    const float* __restrict__ samp,         // (O,P,63,8)
    const float* __restrict__ addr,         // (O,P,63,10)
    const float* __restrict__ hin,          // [cellsIn][128] f32
    float* __restrict__ hout,               // [rowsOut][128] f32
    int lw, int last)
{
    __shared__ unsigned short Blds[21504];  // 43008 B = 2688 float4 (hi+lo!)

    const int tid = threadIdx.x;
    const int lane = tid & 63;
    const int wid = tid >> 6;
    const int j15 = lane & 15;
    const int qr = lane >> 4;
    const int c0 = blockIdx.x * (NW * 16);
    const int c0w = c0 + wid * 16;
    const int o = c0w >> (lw + 6);          // uniform per wave

    f32x4 acc[28];
    #pragma unroll
    for (int t = 0; t < 28; ++t) acc[t] = (f32x4){0.f, 0.f, 0.f, 0.f};

    // ---- build X A-frag in-register (row = c0w + j15, k slice per quarter);
    //      k=18 (qr=2, elem 2) carries 1.0 for the bias row ----
    const int w = 1 << lw;
    const int cm = c0w + j15;
    const int opm = cm >> lw;
    const int nodem = w - 1 + (cm & (w - 1));
    const size_t nb = (size_t)opm * 63 + nodem;
    float xv0=0.f,xv1=0.f,xv2=0.f,xv3=0.f,xv4=0.f,xv5=0.f,xv6=0.f,xv7=0.f;
    if (qr == 0) {
        const float4* s4 = (const float4*)(samp + nb * 8);
        float4 a = s4[0], b = s4[1];
        xv0=a.x; xv1=a.y; xv2=a.z; xv3=a.w; xv4=b.x; xv5=b.y; xv6=b.z; xv7=b.w;
    } else if (qr == 1) {
        const float2* a2 = (const float2*)(addr + nb * 10);
        float2 e0=a2[0], e1=a2[1], e2=a2[2], e3=a2[3];
        xv0=e0.x; xv1=e0.y; xv2=e1.x; xv3=e1.y; xv4=e2.x; xv5=e2.y; xv6=e3.x; xv7=e3.y;
    } else if (qr == 2) {
        xv0 = addr[nb * 10 + 8]; xv1 = addr[nb * 10 + 9];
        xv2 = 1.0f;                          // bias row k=18
    }
    bf16x8 axhi, axlo;
    #define CVT(e, val) { unsigned short hh = f2bf(val); \
        axhi[e] = (short)hh; axlo[e] = (short)f2bf((val) - bf2f(hh)); }
    CVT(0, xv0) CVT(1, xv1) CVT(2, xv2) CVT(3, xv3)
    CVT(4, xv4) CVT(5, xv5) CVT(6, xv6) CVT(7, xv7)
    #undef CVT

    // ---- kstep loop: stage slab -> (load A slice) -> barrier -> MFMA ----
    #pragma unroll
    for (int ks = 0; ks <= (HASH ? 4 : 0); ++ks) {
        if (ks) __syncthreads();            // protect slab overwrite
        {
            // ks0 slab is per-o; H slabs start at 64*21504
            const unsigned short* gs = Bg + (ks == 0 ? (size_t)o * 21504
                                          : (size_t)(63 + ks) * 21504);
            const float4* src = (const float4*)gs;
            float4* dst = (float4*)Blds;
            // slab = 21504 ush * 2 B / 16 B = 2688 float4 (hi AND lo planes)
            #pragma unroll
            for (int i = tid; i < 2688; i += NW * 64) dst[i] = src[i];
        }
        bf16x8 ahi, alo;
        if (ks) { // A slice from f32 h, split hi/lo in-register
            const float* ap = hin + (size_t)(c0w + j15) * 128 + (ks - 1) * 32 + qr * 8;
            float4 a0 = *(const float4*)ap;
            float4 a1 = *(const float4*)(ap + 4);
            #define CVT(e, val) { unsigned short hh = f2bf(val); \
                ahi[e] = (short)hh; alo[e] = (short)f2bf((val) - bf2f(hh)); }
            CVT(0, a0.x) CVT(1, a0.y) CVT(2, a0.z) CVT(3, a0.w)
            CVT(4, a1.x) CVT(5, a1.y) CVT(6, a1.z) CVT(7, a1.w)
            #undef CVT
        }
        __syncthreads();

        if (ks == 0) {
            #pragma unroll
            for (int s = 0; s < 21; ++s) {
                const unsigned short* bb = Blds + ((s * 4 + qr) * 16 + j15) * 8;
                bf16x8 bhi = *(const bf16x8*)bb;
                bf16x8 blo = *(const bf16x8*)(bb + 10752);
                acc[s] = __builtin_amdgcn_mfma_f32_16x16x32_bf16(axhi, bhi, acc[s], 0, 0, 0);
                acc[s] = __builtin_amdgcn_mfma_f32_16x16x32_bf16(axlo, bhi, acc[s], 0, 0, 0);
                acc[s] = __builtin_amdgcn_mfma_f32_16x16x32_bf16(axhi, blo, acc[s], 0, 0, 0);
            }
        } else if constexpr (HASH) {
            #pragma unroll
            for (int s = 0; s < 21; ++s) {
                const int d = (s < 14) ? s : s + 7;
                const unsigned short* bb = Blds + ((s * 4 + qr) * 16 + j15) * 8;
                bf16x8 bhi = *(const bf16x8*)bb;
                bf16x8 blo = *(const bf16x8*)(bb + 10752);
                acc[d] = __builtin_amdgcn_mfma_f32_16x16x32_bf16(ahi, bhi, acc[d], 0, 0, 0);
                acc[d] = __builtin_amdgcn_mfma_f32_16x16x32_bf16(alo, bhi, acc[d], 0, 0, 0);
                acc[d] = __builtin_amdgcn_mfma_f32_16x16x32_bf16(ahi, blo, acc[d], 0, 0, 0);
            }
        }
    }

    // ---- epilogue: gates, pair-sum (regs are consecutive rows), f32 store ----
    #pragma unroll
    for (int t = 0; t < 7; ++t) {
        const int u = t * 16 + j15;
        const float bh = (u < 100) ? bhh[200 + u] : 0.f;  // h_n bias
        float hv0, hv1, hv2, hv3;
        #define GATE(reg, hvout) { \
            float rr = sigmoidf_(acc[t][reg]); \
            float zz = sigmoidf_(acc[t + 7][reg]); \
            float nn = tanhf_(acc[t + 14][reg] + rr * (acc[t + 21][reg] + bh)); \
            float hcv = 0.f; \
            if constexpr (HASH) hcv = hin[(size_t)(c0w + qr * 4 + reg) * 128 + u]; \
            hvout = nn + zz * (hcv - nn); }
        GATE(0, hv0) GATE(1, hv1) GATE(2, hv2) GATE(3, hv3)
        #undef GATE
        if (last) {
            float* r0 = hout + (size_t)(c0w + qr * 4) * 128 + u;
            r0[0]   = hv0;
            r0[128] = hv1;
            r0[256] = hv2;
            r0[384] = hv3;
        } else {
            float* r0 = hout + (size_t)((c0w >> 1) + qr * 2) * 128 + u;
            r0[0]   = hv0 + hv1;
            r0[128] = hv2 + hv3;
        }
    }
    // zero k-padding cols 112..127 for the next level's A reads
    {
        const int u2 = 112 + j15;
        if (last) {
            #pragma unroll
            for (int reg = 0; reg < 4; ++reg)
                hout[(size_t)(c0w + qr * 4 + reg) * 128 + u2] = 0.f;
        } else {
            #pragma unroll
            for (int p = 0; p < 2; ++p)
                hout[(size_t)((c0w >> 1) + qr * 2 + p) * 128 + u2] = 0.f;
        }
    }
}

// ---------------------------------------------------------------------------
// MLP head + logsumexp over 64 particles. Block = one o; lane = particle.
// ---------------------------------------------------------------------------
__global__ __launch_bounds__(64) void mlp_lse(
    const float* __restrict__ h0,   // [4096][128] f32
    const float* __restrict__ W1T,  // [100][50]
    const float* __restrict__ b1,
    const float* __restrict__ W2T,  // [50][25]
    const float* __restrict__ b2,
    const float* __restrict__ W3,
    const float* __restrict__ b3,
    float* __restrict__ out)
{
    __shared__ float hs[64 * 101];
    const int o = blockIdx.x;
    const int p = threadIdx.x;
    for (int f = p; f < 6400; f += 64) {
        int cl = f / 100, g = f - cl * 100;
        hs[cl * 101 + g] = h0[(size_t)(o * 64 + cl) * 128 + g];
    }
    __syncthreads();

    float y1[50];
    #pragma unroll
    for (int j = 0; j < 50; ++j) y1[j] = b1[j];
    #pragma unroll 2
    for (int g = 0; g < 100; ++g) {
        float rg = hs[p * 101 + g];
        const float* wr = W1T + g * 50;
        #pragma unroll
        for (int j = 0; j < 50; ++j) y1[j] = fmaf(rg, wr[j], y1[j]);
    }

    float y2[25];
    #pragma unroll
    for (int i = 0; i < 25; ++i) y2[i] = b2[i];
    #pragma unroll
    for (int j = 0; j < 50; ++j) {
        float v = fmaxf(y1[j], 0.0f);
        const float* wr = W2T + j * 25;
        #pragma unroll
        for (int i = 0; i < 25; ++i) y2[i] = fmaf(v, wr[i], y2[i]);
    }

    float cv = b3[0];
    #pragma unroll
    for (int i = 0; i < 25; ++i) cv = fmaf(fmaxf(y2[i], 0.0f), W3[i], cv);

    float m = cv;
    #pragma unroll
    for (int s = 1; s < 64; s <<= 1) m = fmaxf(m, __shfl_xor(m, s));
    float e = __expf(cv - m);
    #pragma unroll
    for (int s = 1; s < 64; s <<= 1) e += __shfl_xor(e, s);
    if (p == 0) out[o] = m + __logf(e) - 4.1588830833596715f; // log(64)
}

// ---------------------------------------------------------------------------
extern "C" void kernel_launch(void* const* d_in, const int* in_sizes, int n_in,
                              void* d_out, int out_size, void* d_ws, size_t ws_size,
                              hipStream_t stream)
{
    const float* obs  = (const float*)d_in[0];
    const float* samp = (const float*)d_in[1];
    const float* addr = (const float*)d_in[2];
    const float* W_ih = (const float*)d_in[3];
    const float* W_hh = (const float*)d_in[4];
    const float* b_ih = (const float*)d_in[5];
    const float* b_hh = (const float*)d_in[6];
    const float* W1   = (const float*)d_in[7];
    const float* b1   = (const float*)d_in[8];
    const float* W2   = (const float*)d_in[9];
    const float* b2   = (const float*)d_in[10];
    const float* W3   = (const float*)d_in[11];
    const float* b3   = (const float*)d_in[12];
    float* out = (float*)d_out;

    float* ws = (float*)d_ws;
    // Bg: 68 slabs * 21504 ush = 1462272 ush = 731136 floats
    unsigned short* Bg = (unsigned short*)ws;
    float* W1T = ws + 731136;                 // 5000
    float* W2T = ws + 736136;                 // 1250
    float* hA  = ws + 737392;                 // 65536*128 = 8388608 f
    float* hB  = ws + 9126000;                // 32768*128 = 4194304 f

    // threads: 688128 (ks0 slabs) + 43008 (H slabs) + 5000 + 1250 = 737386
    precompute_kernel<<<(737386 + 63) / 64, 64, 0, stream>>>(
        obs, W_ih, W_hh, b_ih, b_hh, W1, W2, Bg, W1T, W2T);

    // leaf lw=5: 131072 cells -> pairsum 65536 rows (hA)
    gru_level<false, 8><<<1024, 512, 0, stream>>>(Bg, b_hh, samp, addr,
        nullptr, hA, 5, 0);
    // L4: 65536 cells (hA) -> 32768 (hB)
    gru_level<true, 8><<<512, 512, 0, stream>>>(Bg, b_hh, samp, addr, hA, hB, 4, 0);
    // L3: 32768 (hB) -> 16384 (hA)
    gru_level<true, 8><<<256, 512, 0, stream>>>(Bg, b_hh, samp, addr, hB, hA, 3, 0);
    // L2: 16384 (hA) -> 8192 (hB)
    gru_level<true, 4><<<256, 256, 0, stream>>>(Bg, b_hh, samp, addr, hA, hB, 2, 0);
    // L1: 8192 (hB) -> 4096 (hA)
    gru_level<true, 4><<<128, 256, 0, stream>>>(Bg, b_hh, samp, addr, hB, hA, 1, 0);
    // L0 (root, last): 4096 (hA) -> 4096 (hB)
    gru_level<true, 4><<<64, 256, 0, stream>>>(Bg, b_hh, samp, addr, hA, hB, 0, 1);

    mlp_lse<<<64, 64, 0, stream>>>(hB, W1T, b1, W2T, b2, W3, b3, out);
}

// Round 11
// 200.982 us; speedup vs baseline: 1.1614x; 1.1614x over previous
//
#include <hip/hip_runtime.h>
#include <hip/hip_bf16.h>

typedef __attribute__((ext_vector_type(8))) short bf16x8;
typedef __attribute__((ext_vector_type(4))) float f32x4;

__device__ __forceinline__ float sigmoidf_(float x){ return 1.0f/(1.0f+__expf(-x)); }
__device__ __forceinline__ float tanhf_(float x){ return 1.0f - 2.0f/(1.0f+__expf(2.0f*x)); }
__device__ __forceinline__ unsigned short f2bf(float f){
    __hip_bfloat16 b = __float2bfloat16(f);
    return *reinterpret_cast<unsigned short*>(&b);
}
__device__ __forceinline__ float bf2f(unsigned short u){
    __hip_bfloat16 b = *reinterpret_cast<__hip_bfloat16*>(&u);
    return __bfloat162float(b);
}

// ---------------------------------------------------------------------------
// Layouts:
//  Bg (ushort): 68 slabs of 21504 ush (= 43008 B = 2688 float4 each).
//   slab = [plane hi/lo][21 slots][4 qr][16 j][8 e]; plane stride 10752 ush.
//   Slabs 0..63  = per-o ks0 slabs: slots 0..20 = tiles 0..20 (r,z,i_n);
//     k rows: kk<18 -> W_ih[gate][100+kk]; kk==18 -> BIAS (b_ih(+b_hh for r/z)
//     + obs[o].W_ih[:, :100]), hi/lo split; kk>18 -> 0. A supplies 1.0 at k=18.
//   Slabs 64..67 = H ksteps 1..4: kh=(ks-1)*32+kk<100 of W_hh;
//     slots 0..13 -> tiles 0..13 (r,z); slots 14..20 -> tiles 21..27 (hn).
//     REGION 3 (hn) uses gate rows 200+u (same n-gate rows as region 2)!
//  h (float32): [rows][128]; cols 112..127 zeroed explicitly.
// ---------------------------------------------------------------------------
__global__ __launch_bounds__(64) void precompute_kernel(
    const float* __restrict__ obs, const float* __restrict__ W_ih,
    const float* __restrict__ W_hh, const float* __restrict__ b_ih,
    const float* __restrict__ b_hh, const float* __restrict__ W1,
    const float* __restrict__ W2,
    unsigned short* __restrict__ Bg,
    float* __restrict__ W1T, float* __restrict__ W2T)
{
    int t = blockIdx.x * 64 + threadIdx.x;
    if (t < 688128) { // ks0 slabs, one per o: 64 * 10752 positions (per plane)
        int o = t / 10752, r = t % 10752;
        int s = r / 512, r2 = r % 512;
        int j = r2 / 32, kk = r2 % 32;
        int region = s / 7;                 // 0=r,1=z,2=i_n
        int u = (s % 7) * 16 + j;
        float wv = 0.f;
        if (u < 100) {
            int gate = region * 100 + u;
            if (kk < 18) {
                wv = W_ih[(size_t)gate * 118 + 100 + kk];
            } else if (kk == 18) { // bias row (old gio)
                wv = b_ih[gate] + (region < 2 ? b_hh[gate] : 0.f);
                const float* orow = obs + o * 100;
                const float* wrow = W_ih + (size_t)gate * 118;
                for (int k = 0; k < 100; ++k) wv = fmaf(orow[k], wrow[k], wv);
            }
        }
        unsigned short h = f2bf(wv);
        unsigned short l = f2bf(wv - bf2f(h));
        int qr = kk >> 3, e = kk & 7;
        size_t base = (size_t)o * 21504 + (size_t)((s * 4 + qr) * 16 + j) * 8 + e;
        Bg[base] = h;
        Bg[base + 10752] = l;
        return;
    }
    t -= 688128;
    if (t < 43008) { // H slabs (ks 1..4): 4 * 10752 positions
        int ks = 1 + t / 10752, r = t % 10752;
        int s = r / 512, r2 = r % 512;
        int j = r2 / 32, kk = r2 % 32;
        int tt = (s < 14) ? s : s + 7;
        int region = tt / 7;
        int u = (tt % 7) * 16 + j;
        float wv = 0.f;
        if (u < 100) {
            // region 3 (h_n) uses the SAME n-gate rows (200+u) as region 2
            int gate = (region == 3 ? 2 : region) * 100 + u;
            int kh = (ks - 1) * 32 + kk;
            if (kh < 100) wv = W_hh[(size_t)gate * 100 + kh];
        }
        unsigned short h = f2bf(wv);
        unsigned short l = f2bf(wv - bf2f(h));
        int qr = kk >> 3, e = kk & 7;
        size_t base = (size_t)(64 + ks - 1) * 21504
                    + (size_t)((s * 4 + qr) * 16 + j) * 8 + e;
        Bg[base] = h;
        Bg[base + 10752] = l;
        return;
    }
    t -= 43008;
    if (t < 5000) { int g = t / 50, j = t % 50; W1T[t] = W1[j * 100 + g]; return; }
    t -= 5000;
    if (t < 1250) { int j = t / 25, i = t % 25; W2T[t] = W2[i * 50 + j]; }
}

// ---------------------------------------------------------------------------
// GRU level via MFMA. Block = NW waves; wave = one 16-cell M-tile.
// acc[28] f32x4 zero-init: tiles 0-6=r, 7-13=z, 14-20=i_n, 21-27=h_n.
// (unchanged from R10 — verified correct)
// ---------------------------------------------------------------------------
template<bool HASH, int NW>
__global__ __launch_bounds__(NW * 64) void gru_level(
    const unsigned short* __restrict__ Bg,  // 68 slabs (see layout)
    const float* __restrict__ bhh,          // b_hh (for h_n bias rows 200+u)
    const float* __restrict__ samp,         // (O,P,63,8)
    const float* __restrict__ addr,         // (O,P,63,10)
    const float* __restrict__ hin,          // [cellsIn][128] f32
    float* __restrict__ hout,               // [rowsOut][128] f32
    int lw, int last)
{
    __shared__ unsigned short Blds[21504];  // 43008 B = 2688 float4 (hi+lo!)

    const int tid = threadIdx.x;
    const int lane = tid & 63;
    const int wid = tid >> 6;
    const int j15 = lane & 15;
    const int qr = lane >> 4;
    const int c0 = blockIdx.x * (NW * 16);
    const int c0w = c0 + wid * 16;
    const int o = c0w >> (lw + 6);          // uniform per wave

    f32x4 acc[28];
    #pragma unroll
    for (int t = 0; t < 28; ++t) acc[t] = (f32x4){0.f, 0.f, 0.f, 0.f};

    const int w = 1 << lw;
    const int cm = c0w + j15;
    const int opm = cm >> lw;
    const int nodem = w - 1 + (cm & (w - 1));
    const size_t nb = (size_t)opm * 63 + nodem;
    float xv0=0.f,xv1=0.f,xv2=0.f,xv3=0.f,xv4=0.f,xv5=0.f,xv6=0.f,xv7=0.f;
    if (qr == 0) {
        const float4* s4 = (const float4*)(samp + nb * 8);
        float4 a = s4[0], b = s4[1];
        xv0=a.x; xv1=a.y; xv2=a.z; xv3=a.w; xv4=b.x; xv5=b.y; xv6=b.z; xv7=b.w;
    } else if (qr == 1) {
        const float2* a2 = (const float2*)(addr + nb * 10);
        float2 e0=a2[0], e1=a2[1], e2=a2[2], e3=a2[3];
        xv0=e0.x; xv1=e0.y; xv2=e1.x; xv3=e1.y; xv4=e2.x; xv5=e2.y; xv6=e3.x; xv7=e3.y;
    } else if (qr == 2) {
        xv0 = addr[nb * 10 + 8]; xv1 = addr[nb * 10 + 9];
        xv2 = 1.0f;                          // bias row k=18
    }
    bf16x8 axhi, axlo;
    #define CVT(e, val) { unsigned short hh = f2bf(val); \
        axhi[e] = (short)hh; axlo[e] = (short)f2bf((val) - bf2f(hh)); }
    CVT(0, xv0) CVT(1, xv1) CVT(2, xv2) CVT(3, xv3)
    CVT(4, xv4) CVT(5, xv5) CVT(6, xv6) CVT(7, xv7)
    #undef CVT

    #pragma unroll
    for (int ks = 0; ks <= (HASH ? 4 : 0); ++ks) {
        if (ks) __syncthreads();
        {
            const unsigned short* gs = Bg + (ks == 0 ? (size_t)o * 21504
                                          : (size_t)(63 + ks) * 21504);
            const float4* src = (const float4*)gs;
            float4* dst = (float4*)Blds;
            #pragma unroll
            for (int i = tid; i < 2688; i += NW * 64) dst[i] = src[i];
        }
        bf16x8 ahi, alo;
        if (ks) {
            const float* ap = hin + (size_t)(c0w + j15) * 128 + (ks - 1) * 32 + qr * 8;
            float4 a0 = *(const float4*)ap;
            float4 a1 = *(const float4*)(ap + 4);
            #define CVT(e, val) { unsigned short hh = f2bf(val); \
                ahi[e] = (short)hh; alo[e] = (short)f2bf((val) - bf2f(hh)); }
            CVT(0, a0.x) CVT(1, a0.y) CVT(2, a0.z) CVT(3, a0.w)
            CVT(4, a1.x) CVT(5, a1.y) CVT(6, a1.z) CVT(7, a1.w)
            #undef CVT
        }
        __syncthreads();

        if (ks == 0) {
            #pragma unroll
            for (int s = 0; s < 21; ++s) {
                const unsigned short* bb = Blds + ((s * 4 + qr) * 16 + j15) * 8;
                bf16x8 bhi = *(const bf16x8*)bb;
                bf16x8 blo = *(const bf16x8*)(bb + 10752);
                acc[s] = __builtin_amdgcn_mfma_f32_16x16x32_bf16(axhi, bhi, acc[s], 0, 0, 0);
                acc[s] = __builtin_amdgcn_mfma_f32_16x16x32_bf16(axlo, bhi, acc[s], 0, 0, 0);
                acc[s] = __builtin_amdgcn_mfma_f32_16x16x32_bf16(axhi, blo, acc[s], 0, 0, 0);
            }
        } else if constexpr (HASH) {
            #pragma unroll
            for (int s = 0; s < 21; ++s) {
                const int d = (s < 14) ? s : s + 7;
                const unsigned short* bb = Blds + ((s * 4 + qr) * 16 + j15) * 8;
                bf16x8 bhi = *(const bf16x8*)bb;
                bf16x8 blo = *(const bf16x8*)(bb + 10752);
                acc[d] = __builtin_amdgcn_mfma_f32_16x16x32_bf16(ahi, bhi, acc[d], 0, 0, 0);
                acc[d] = __builtin_amdgcn_mfma_f32_16x16x32_bf16(alo, bhi, acc[d], 0, 0, 0);
                acc[d] = __builtin_amdgcn_mfma_f32_16x16x32_bf16(ahi, blo, acc[d], 0, 0, 0);
            }
        }
    }

    #pragma unroll
    for (int t = 0; t < 7; ++t) {
        const int u = t * 16 + j15;
        const float bh = (u < 100) ? bhh[200 + u] : 0.f;  // h_n bias
        float hv0, hv1, hv2, hv3;
        #define GATE(reg, hvout) { \
            float rr = sigmoidf_(acc[t][reg]); \
            float zz = sigmoidf_(acc[t + 7][reg]); \
            float nn = tanhf_(acc[t + 14][reg] + rr * (acc[t + 21][reg] + bh)); \
            float hcv = 0.f; \
            if constexpr (HASH) hcv = hin[(size_t)(c0w + qr * 4 + reg) * 128 + u]; \
            hvout = nn + zz * (hcv - nn); }
        GATE(0, hv0) GATE(1, hv1) GATE(2, hv2) GATE(3, hv3)
        #undef GATE
        if (last) {
            float* r0 = hout + (size_t)(c0w + qr * 4) * 128 + u;
            r0[0]   = hv0;
            r0[128] = hv1;
            r0[256] = hv2;
            r0[384] = hv3;
        } else {
            float* r0 = hout + (size_t)((c0w >> 1) + qr * 2) * 128 + u;
            r0[0]   = hv0 + hv1;
            r0[128] = hv2 + hv3;
        }
    }
    {
        const int u2 = 112 + j15;
        if (last) {
            #pragma unroll
            for (int reg = 0; reg < 4; ++reg)
                hout[(size_t)(c0w + qr * 4 + reg) * 128 + u2] = 0.f;
        } else {
            #pragma unroll
            for (int p = 0; p < 2; ++p)
                hout[(size_t)((c0w >> 1) + qr * 2 + p) * 128 + u2] = 0.f;
        }
    }
}

// ---------------------------------------------------------------------------
// MLP head + logsumexp. Block = one o, 256 thr (4 waves); lane = particle.
// All weights staged in LDS; j-dimension of y1 split across waves (no
// reduction: each wave owns y1[j] fully, summing over all g). Wave 0 runs
// the y2/y3/LSE tail after an LDS handoff of y1.
// LDS: 6464 + 5008 + 1250 + 3200 floats = 63.7 KB (< 64 KB cap).
// ---------------------------------------------------------------------------
__global__ __launch_bounds__(256) void mlp_lse(
    const float* __restrict__ h0,   // [4096][128] f32
    const float* __restrict__ W1T,  // [100][50]
    const float* __restrict__ b1,
    const float* __restrict__ W2T,  // [50][25]
    const float* __restrict__ b2,
    const float* __restrict__ W3,
    const float* __restrict__ b3,
    float* __restrict__ out)
{
    __shared__ float hs[64 * 101];   // 6464
    __shared__ float w1s[5008];      // [100][50] (+pad for harmless overread)
    __shared__ float w2s[1250];      // [50][25]
    __shared__ float y1s[64 * 50];   // handoff

    const int o = blockIdx.x;
    const int tid = threadIdx.x;
    const int lane = tid & 63;
    const int wid = tid >> 6;

    for (int f = tid; f < 6400; f += 256) {
        int cl = f / 100, g = f - cl * 100;
        hs[cl * 101 + g] = h0[(size_t)(o * 64 + cl) * 128 + g];
    }
    for (int f = tid; f < 5000; f += 256) w1s[f] = W1T[f];
    for (int f = tid; f < 1250; f += 256) w2s[f] = W2T[f];
    __syncthreads();

    // ---- phase 1: y1[jbase..jbase+jn) per wave, sum over all g ----
    const int jbase = wid * 13;
    const int jn = (wid < 3) ? 13 : 11;       // 13+13+13+11 = 50
    float y1[13];
    #pragma unroll
    for (int jj = 0; jj < 13; ++jj) y1[jj] = b1[jbase + jj < 50 ? jbase + jj : 49];
    #pragma unroll 2
    for (int g = 0; g < 100; ++g) {
        float rg = hs[lane * 101 + g];
        const float* wr = w1s + g * 50 + jbase;
        #pragma unroll
        for (int jj = 0; jj < 13; ++jj) y1[jj] = fmaf(rg, wr[jj], y1[jj]);
    }
    #pragma unroll
    for (int jj = 0; jj < 13; ++jj)
        if (jj < jn) y1s[lane * 50 + jbase + jj] = y1[jj];
    __syncthreads();
    if (wid != 0) return;

    // ---- phase 2 (wave 0): y2, y3, logsumexp ----
    const int p = lane;
    float y2[25];
    #pragma unroll
    for (int i = 0; i < 25; ++i) y2[i] = b2[i];
    #pragma unroll 2
    for (int j = 0; j < 50; ++j) {
        float v = fmaxf(y1s[p * 50 + j], 0.0f);
        const float* wr = w2s + j * 25;
        #pragma unroll
        for (int i = 0; i < 25; ++i) y2[i] = fmaf(v, wr[i], y2[i]);
    }

    float cv = b3[0];
    #pragma unroll
    for (int i = 0; i < 25; ++i) cv = fmaf(fmaxf(y2[i], 0.0f), W3[i], cv);

    float m = cv;
    #pragma unroll
    for (int s = 1; s < 64; s <<= 1) m = fmaxf(m, __shfl_xor(m, s));
    float e = __expf(cv - m);
    #pragma unroll
    for (int s = 1; s < 64; s <<= 1) e += __shfl_xor(e, s);
    if (p == 0) out[o] = m + __logf(e) - 4.1588830833596715f; // log(64)
}

// ---------------------------------------------------------------------------
extern "C" void kernel_launch(void* const* d_in, const int* in_sizes, int n_in,
                              void* d_out, int out_size, void* d_ws, size_t ws_size,
                              hipStream_t stream)
{
    const float* obs  = (const float*)d_in[0];
    const float* samp = (const float*)d_in[1];
    const float* addr = (const float*)d_in[2];
    const float* W_ih = (const float*)d_in[3];
    const float* W_hh = (const float*)d_in[4];
    const float* b_ih = (const float*)d_in[5];
    const float* b_hh = (const float*)d_in[6];
    const float* W1   = (const float*)d_in[7];
    const float* b1   = (const float*)d_in[8];
    const float* W2   = (const float*)d_in[9];
    const float* b2   = (const float*)d_in[10];
    const float* W3   = (const float*)d_in[11];
    const float* b3   = (const float*)d_in[12];
    float* out = (float*)d_out;

    float* ws = (float*)d_ws;
    // Bg: 68 slabs * 21504 ush = 1462272 ush = 731136 floats
    unsigned short* Bg = (unsigned short*)ws;
    float* W1T = ws + 731136;                 // 5000
    float* W2T = ws + 736136;                 // 1250
    float* hA  = ws + 737392;                 // 65536*128 = 8388608 f
    float* hB  = ws + 9126000;                // 32768*128 = 4194304 f

    // threads: 688128 (ks0 slabs) + 43008 (H slabs) + 5000 + 1250 = 737386
    precompute_kernel<<<(737386 + 63) / 64, 64, 0, stream>>>(
        obs, W_ih, W_hh, b_ih, b_hh, W1, W2, Bg, W1T, W2T);

    // leaf lw=5: 131072 cells -> pairsum 65536 rows (hA)
    gru_level<false, 8><<<1024, 512, 0, stream>>>(Bg, b_hh, samp, addr,
        nullptr, hA, 5, 0);
    // L4: 65536 cells (hA) -> 32768 (hB)
    gru_level<true, 8><<<512, 512, 0, stream>>>(Bg, b_hh, samp, addr, hA, hB, 4, 0);
    // L3: 32768 (hB) -> 16384 (hA)
    gru_level<true, 8><<<256, 512, 0, stream>>>(Bg, b_hh, samp, addr, hB, hA, 3, 0);
    // L2: 16384 (hA) -> 8192 (hB)
    gru_level<true, 4><<<256, 256, 0, stream>>>(Bg, b_hh, samp, addr, hA, hB, 2, 0);
    // L1: 8192 (hB) -> 4096 (hA)
    gru_level<true, 4><<<128, 256, 0, stream>>>(Bg, b_hh, samp, addr, hB, hA, 1, 0);
    // L0 (root, last): 4096 (hA) -> 4096 (hB)
    gru_level<true, 4><<<64, 256, 0, stream>>>(Bg, b_hh, samp, addr, hA, hB, 0, 1);

    mlp_lse<<<64, 256, 0, stream>>>(hB, W1T, b1, W2T, b2, W3, b3, out);
}